// Round 8
// baseline (125.263 us; speedup 1.0000x reference)
//
#include <hip/hip_runtime.h>
#include <stdint.h>

typedef unsigned short u16;
typedef __attribute__((ext_vector_type(4))) float f32x4;
typedef __attribute__((ext_vector_type(16))) float f32x16;
typedef __attribute__((ext_vector_type(8))) __bf16 bf16x8;
typedef __attribute__((ext_vector_type(8))) unsigned short u16x8;
typedef __attribute__((ext_vector_type(4))) unsigned short u16x4;

#define DIM_    1024
#define NHEADS_ 16
#define HD_     64
#define BB_     2
#define NN_     2048
#define MM_     2048

// 0.125 * log2(e): folded into Q projection so softmax runs in base-2.
#define QSCALE 0.180336884f

__device__ inline u16 f32_to_bf16u(float f) {
  union { float f; uint32_t u; } x; x.f = f;
  uint32_t r = x.u + 0x7FFFu + ((x.u >> 16) & 1u);
  return (u16)(r >> 16);
}

__device__ inline void gload_lds16(const u16* g, u16* l) {
  u16* gnc = const_cast<u16*>(g);
  __builtin_amdgcn_global_load_lds(
      (__attribute__((address_space(1))) void*)gnc,
      (__attribute__((address_space(3))) void*)l, 16, 0, 0);
}

__device__ inline uint32_t cvt_pk_bf16(float lo, float hi) {
  uint32_t r;
  asm("v_cvt_pk_bf16_f32 %0, %1, %2" : "=v"(r) : "v"(lo), "v"(hi));
  return r;
}
__device__ inline void permlane32_swap(uint32_t& a, uint32_t& b) {
  asm("v_permlane32_swap_b32 %0, %1" : "+v"(a), "+v"(b));
}

// ---------------- fused cast fp32 -> bf16 (all 6 tensors, one launch) ------
__global__ void cast_all(const float* s0, u16* d0, const float* s1, u16* d1,
                         const float* s2, u16* d2, const float* s3, u16* d3,
                         const float* s4, u16* d4, const float* s5, u16* d5) {
  const float* s; u16* d; int n4;
  switch (blockIdx.y) {
    case 0: s = s0; d = d0; n4 = (BB_ * NN_ * DIM_) / 4; break;
    case 1: s = s1; d = d1; n4 = (BB_ * MM_ * DIM_) / 4; break;
    case 2: s = s2; d = d2; n4 = (DIM_ * DIM_) / 4; break;
    case 3: s = s3; d = d3; n4 = (DIM_ * DIM_) / 4; break;
    case 4: s = s4; d = d4; n4 = (DIM_ * DIM_) / 4; break;
    default: s = s5; d = d5; n4 = (DIM_ * DIM_) / 4; break;
  }
  int stride = gridDim.x * blockDim.x;
  for (int i = blockIdx.x * blockDim.x + threadIdx.x; i < n4; i += stride) {
    float4 f = reinterpret_cast<const float4*>(s)[i];
    u16x4 u;
    u.x = f32_to_bf16u(f.x);
    u.y = f32_to_bf16u(f.y);
    u.z = f32_to_bf16u(f.z);
    u.w = f32_to_bf16u(f.w);
    reinterpret_cast<u16x4*>(d)[i] = u;
  }
}

// ---------------- GEMM core: C[M,N] = A * B^T + bias, 128x128 tile --------
#define BM 128
#define BN 128
#define BK 64

template <bool BF16OUT>
__device__ __forceinline__
void gemm_body(const u16* __restrict__ A, const u16* __restrict__ Bm,
               const float* __restrict__ bias, void* __restrict__ Cout,
               int M, int N, int K, float scale,
               u16* As /*2*BM*BK*/, u16* Bs /*2*BN*BK*/) {
  const int tid  = threadIdx.x;
  const int lane = tid & 63;
  const int wid  = tid >> 6;
  const int wr = wid >> 2, wc = wid & 3;          // 2 x 4 wave grid
  const int fr = lane & 15, fq = lane >> 4;
  const int bm = blockIdx.x, bn = blockIdx.y;
  const int lrow = lane >> 3;                     // 0..7
  const int scol = (((lane & 7) ^ lrow) * 8);     // pre-swizzled source col

  f32x4 acc[4][2];
  #pragma unroll
  for (int m = 0; m < 4; ++m)
    #pragma unroll
    for (int n = 0; n < 2; ++n)
      acc[m][n] = f32x4{0.f, 0.f, 0.f, 0.f};

  const int NT = K / BK;

  auto stage = [&](int buf, int t) {
    int k0 = t * BK;
    #pragma unroll
    for (int c = 0; c < 2; ++c) {
      int ch  = wid * 2 + c;           // 0..15
      int row = ch * 8 + lrow;         // 0..127
      gload_lds16(A  + (size_t)(bm * BM + row) * K + k0 + scol, &As[buf * BM * BK + ch * 512]);
      gload_lds16(Bm + (size_t)(bn * BN + row) * K + k0 + scol, &Bs[buf * BN * BK + ch * 512]);
    }
  };

  stage(0, 0);
  __syncthreads();
  int cur = 0;
  for (int t = 0; t < NT; ++t) {
    if (t + 1 < NT) stage(cur ^ 1, t + 1);
    #pragma unroll
    for (int ks = 0; ks < 2; ++ks) {
      bf16x8 af[4], bfr[2];
      #pragma unroll
      for (int m = 0; m < 4; ++m)
        af[m] = *reinterpret_cast<const bf16x8*>(
            &As[cur * BM * BK + (wr * 64 + m * 16 + fr) * BK + (((ks * 4 + fq) ^ (fr & 7)) * 8)]);
      #pragma unroll
      for (int n = 0; n < 2; ++n)
        bfr[n] = *reinterpret_cast<const bf16x8*>(
            &Bs[cur * BN * BK + (wc * 32 + n * 16 + fr) * BK + (((ks * 4 + fq) ^ (fr & 7)) * 8)]);
      __builtin_amdgcn_s_setprio(1);
      #pragma unroll
      for (int m = 0; m < 4; ++m)
        #pragma unroll
        for (int n = 0; n < 2; ++n)
          acc[m][n] = __builtin_amdgcn_mfma_f32_16x16x32_bf16(af[m], bfr[n], acc[m][n], 0, 0, 0);
      __builtin_amdgcn_s_setprio(0);
    }
    __syncthreads();
    cur ^= 1;
  }

  #pragma unroll
  for (int n = 0; n < 2; ++n) {
    int col = bn * BN + wc * 32 + n * 16 + fr;
    float bv = bias[col];
    #pragma unroll
    for (int m = 0; m < 4; ++m) {
      #pragma unroll
      for (int i = 0; i < 4; ++i) {
        int row = bm * BM + wr * 64 + m * 16 + fq * 4 + i;
        float v = (acc[m][n][i] + bv) * scale;
        if (BF16OUT)
          ((u16*)Cout)[(size_t)row * N + col] = f32_to_bf16u(v);
        else
          ((float*)Cout)[(size_t)row * N + col] = v;
      }
    }
  }
}

// Fused Q/K/V projection: grid.z selects {x1*Wq^T+bq, x2*Wk^T+bk, x2*Wv^T+bv}.
__global__ __launch_bounds__(512)
void gemm_qkv(const u16* __restrict__ x1b, const u16* __restrict__ x2b,
              const u16* __restrict__ Wqb, const float* __restrict__ bq, u16* qb,
              const u16* __restrict__ Wkb, const float* __restrict__ bk, u16* kb,
              const u16* __restrict__ Wvb, const float* __restrict__ bv, u16* vb) {
  __shared__ __align__(16) u16 As[2 * BM * BK];
  __shared__ __align__(16) u16 Bs[2 * BN * BK];
  const u16* A; const u16* W; const float* bias; u16* C; float scale;
  switch (blockIdx.z) {
    case 0:  A = x1b; W = Wqb; bias = bq; C = qb; scale = QSCALE; break;
    case 1:  A = x2b; W = Wkb; bias = bk; C = kb; scale = 1.0f;   break;
    default: A = x2b; W = Wvb; bias = bv; C = vb; scale = 1.0f;   break;
  }
  gemm_body<true>(A, W, bias, C, BB_ * NN_, DIM_, DIM_, scale, As, Bs);
}

// O projection (fp32 out).
__global__ __launch_bounds__(512)
void gemm_o(const u16* __restrict__ A, const u16* __restrict__ W,
            const float* __restrict__ bias, float* __restrict__ C) {
  __shared__ __align__(16) u16 As[2 * BM * BK];
  __shared__ __align__(16) u16 Bs[2 * BN * BK];
  gemm_body<false>(A, W, bias, C, BB_ * NN_, DIM_, DIM_, 1.0f, As, Bs);
}

// ---------------- flash attention, 32x32 MFMA ----------------
// 512 blocks (XCD-swizzled: all 16 q-blocks of a (b,h) on one XCD's L2),
// 512 threads = 8 waves = 4 q-groups (32 rows) x 2 kv-halves (32 each).
// Swapped QK^T via mfma_32x32x16(K,Q) -> S^T[kv][q] in 16 f32 regs.
// P stays IN REGISTERS: cvt_pk_bf16 + permlane32_swap redistribute S^T into
// the PV B-fragment (T12). No-max base-2 softmax (scale folded into Q proj).
// l via per-lane f32 partial sums. kv-half split -> one O/l cross-wave
// reduction + LDS transpose at the end (coalesced bf16 O store).
#define QB 128
#define KVB 64

__global__ __launch_bounds__(512)
void attn_fwd(const u16* __restrict__ qg, const u16* __restrict__ kg,
              const u16* __restrict__ vg, u16* __restrict__ og) {
  __shared__ __align__(16) u16 Ks[4][KVB * HD_];    // 4 x 8 KB
  __shared__ __align__(16) u16 VTs[4][HD_ * KVB];   // 4 x 8 KB
  const int tid = threadIdx.x, lane = tid & 63, wid = tid >> 6;
  const int hi = lane >> 5;          // half-wave index
  const int l31 = lane & 31;
  const int wq = wid >> 1, wk = wid & 1;

  // XCD-aware swizzle (bijective: 512 = 8 xcd * 16 r * 4 gg)
  int lin = blockIdx.x + gridDim.x * (blockIdx.y + gridDim.y * blockIdx.z);
  int xcd = lin & 7, slot = lin >> 3;
  int r = slot & 15, gg2 = slot >> 4;
  int g = xcd + 8 * gg2;             // bh group 0..31
  int h = g & 15, b = g >> 4;

  const size_t base_q  = (size_t)b * NN_ * DIM_ + (size_t)h * HD_;
  const size_t base_kv = (size_t)b * MM_ * DIM_ + (size_t)h * HD_;
  const int lrow = lane >> 3;
  const int scol = (((lane & 7) ^ lrow) * 8);   // pre-swizzled K source col

  // Q fragments, B-layout [16 d][32 q]: lane holds Q[q=l31][step*16+hi*8+j]
  bf16x8 qf[4];
  const int qrow = r * QB + wq * 32 + l31;
  #pragma unroll
  for (int step = 0; step < 4; ++step)
    qf[step] = *reinterpret_cast<const bf16x8*>(
        qg + base_q + (size_t)qrow * DIM_ + step * 16 + hi * 8);

  f32x16 oacc[2];
  #pragma unroll
  for (int dgrp = 0; dgrp < 2; ++dgrp)
    #pragma unroll
    for (int rg = 0; rg < 16; ++rg) oacc[dgrp][rg] = 0.f;
  float l_run = 0.f;

  const int NT = MM_ / KVB;

  auto stageK = [&](int buf, int t) {
    int kv0 = t * KVB;
    int row = wid * 8 + lrow;   // 0..63
    gload_lds16(kg + base_kv + (size_t)(kv0 + row) * DIM_ + scol, &Ks[buf][wid * 512]);
  };
  auto loadV = [&](int t, u16x8& vpre) {
    int kv0 = t * KVB;
    vpre = *reinterpret_cast<const u16x8*>(vg + base_kv + (size_t)(kv0 + lane) * DIM_ + wid * 8);
  };
  auto writeVT = [&](int buf, const u16x8& vpre) {
    #pragma unroll
    for (int j = 0; j < 8; ++j)
      VTs[buf][(wid * 8 + j) * KVB + (((lane >> 3) ^ j) * 8) + (lane & 7)] = vpre[j];
  };

  union PB { uint32_t w[4]; bf16x8 v; };

  auto compute = [&](int buf) {
    // ---- QK^T swapped (32x32x16): S^T[kv=wk half][q] ----
    f32x16 s;
    #pragma unroll
    for (int rg = 0; rg < 16; ++rg) s[rg] = 0.f;
    __builtin_amdgcn_s_setprio(1);
    #pragma unroll
    for (int step = 0; step < 4; ++step) {
      bf16x8 kf = *reinterpret_cast<const bf16x8*>(
          (const char*)&Ks[buf][0] + (wk * 32 + l31) * 128 + (((step * 2 + hi) ^ (lane & 7)) * 16));
      s = __builtin_amdgcn_mfma_f32_32x32x16_bf16(kf, qf[step], s, 0, 0, 0);
    }
    __builtin_amdgcn_s_setprio(0);

    // ---- no-max softmax: p = exp2(s); l partial sum ----
    float p[16];
    #pragma unroll
    for (int rg = 0; rg < 16; ++rg) p[rg] = __builtin_amdgcn_exp2f(s[rg]);
    float lp = 0.f;
    #pragma unroll
    for (int rg = 0; rg < 16; ++rg) lp += p[rg];
    l_run += lp;

    // ---- pack P^T into PV B-frags in-register (cvt_pk + permlane32_swap) --
    // lane(hi) holds kv_local {0..3,8..11}+4hi per u-group; B-frag needs
    // kv_local = u*16 + hi*8 + j. swap(cvtpk(p0,p1),cvtpk(p4,p5)) -> w0,w2.
    PB pb[2];
    #pragma unroll
    for (int u = 0; u < 2; ++u) {
      uint32_t x0 = cvt_pk_bf16(p[u * 8 + 0], p[u * 8 + 1]);
      uint32_t y0 = cvt_pk_bf16(p[u * 8 + 4], p[u * 8 + 5]);
      permlane32_swap(x0, y0);
      uint32_t x1 = cvt_pk_bf16(p[u * 8 + 2], p[u * 8 + 3]);
      uint32_t y1 = cvt_pk_bf16(p[u * 8 + 6], p[u * 8 + 7]);
      permlane32_swap(x1, y1);
      pb[u].w[0] = x0; pb[u].w[1] = x1; pb[u].w[2] = y0; pb[u].w[3] = y1;
    }

    // ---- PV (32x32x16): O^T[d][q] += V^T[d][kv] * P^T[kv][q] ----
    __builtin_amdgcn_s_setprio(1);
    #pragma unroll
    for (int dgrp = 0; dgrp < 2; ++dgrp)
      #pragma unroll
      for (int u = 0; u < 2; ++u) {
        bf16x8 vf = *reinterpret_cast<const bf16x8*>(
            (const char*)&VTs[buf][0] + (dgrp * 32 + l31) * 128 +
            (((wk * 4 + u * 2 + hi) ^ (lane & 7)) * 16));
        oacc[dgrp] = __builtin_amdgcn_mfma_f32_32x32x16_bf16(vf, pb[u].v, oacc[dgrp], 0, 0, 0);
      }
    __builtin_amdgcn_s_setprio(0);
  };

  // prologue: stage tiles 0,1
  {
    u16x8 v0, v1;
    loadV(0, v0);
    loadV(1, v1);
    stageK(0, 0);
    stageK(1, 1);
    writeVT(0, v0);
    writeVT(1, v1);
    __syncthreads();
  }

  // main loop: 2 tiles per iteration, ONE barrier per iteration.
  for (int it = 0; it < NT / 2; ++it) {
    int t0 = 2 * it;
    u16x8 vpre0, vpre1;
    bool pre = (t0 + 2 < NT);
    if (pre) {
      loadV(t0 + 2, vpre0);
      loadV(t0 + 3, vpre1);
      stageK((t0 + 2) & 3, t0 + 2);
      stageK((t0 + 3) & 3, t0 + 3);
    }
    compute(t0 & 3);
    compute((t0 + 1) & 3);
    if (pre) {
      writeVT((t0 + 2) & 3, vpre0);
      writeVT((t0 + 3) & 3, vpre1);
    }
    __syncthreads();
  }

  // ---- epilogue: cross-wk O/l reduction + LDS transpose + coalesced store --
  // (loop's final barrier already fenced all LDS reads; Ks/VTs reusable)
  float* Od = (float*)&Ks[0][0];                       // [4][32][64] f32 = 32 KB
  float* Ls = (float*)&VTs[0][0];                      // [4][2][32]  f32 = 1 KB
  u16*  Of  = (u16*)((char*)&VTs[0][0] + 1024);        // [4][32][64] bf16 = 16 KB

  if (wk == 1) {
    #pragma unroll
    for (int dgrp = 0; dgrp < 2; ++dgrp)
      #pragma unroll
      for (int rg = 0; rg < 16; ++rg) {
        int d = dgrp * 32 + (rg & 3) + 8 * (rg >> 2) + 4 * hi;
        Od[(wq * 32 + l31) * 64 + d] = oacc[dgrp][rg];
      }
    Ls[wq * 64 + hi * 32 + l31] = l_run;
  }
  __syncthreads();
  if (wk == 0) {
    #pragma unroll
    for (int dgrp = 0; dgrp < 2; ++dgrp)
      #pragma unroll
      for (int rg = 0; rg < 16; ++rg) {
        int d = dgrp * 32 + (rg & 3) + 8 * (rg >> 2) + 4 * hi;
        oacc[dgrp][rg] += Od[(wq * 32 + l31) * 64 + d];
      }
    float lown = l_run + __shfl_xor(l_run, 32, 64);
    float lfull = lown + Ls[wq * 64 + l31] + Ls[wq * 64 + 32 + l31];
    float inv = 1.f / lfull;
    #pragma unroll
    for (int dgrp = 0; dgrp < 2; ++dgrp)
      #pragma unroll
      for (int rg = 0; rg < 16; ++rg) {
        int d = dgrp * 32 + (rg & 3) + 8 * (rg >> 2) + 4 * hi;
        Of[(wq * 32 + l31) * 64 + d] = f32_to_bf16u(oacc[dgrp][rg] * inv);
      }
  }
  __syncthreads();
  // cooperative coalesced store: 128 q-rows x 128 B
  #pragma unroll
  for (int itr = 0; itr < 2; ++itr) {
    int idx = itr * 512 + tid;   // 0..1023
    int qq = idx >> 3;           // 0..127
    int ck = idx & 7;            // 16B chunk
    u16x8 v = *reinterpret_cast<const u16x8*>(&Of[qq * 64 + ck * 8]);
    *reinterpret_cast<u16x8*>(og + base_q + (size_t)(r * QB + qq) * DIM_ + ck * 8) = v;
  }
}

// ---------------- launch ----------------
extern "C" void kernel_launch(void* const* d_in, const int* in_sizes, int n_in,
                              void* d_out, int out_size, void* d_ws, size_t ws_size,
                              hipStream_t stream) {
  (void)in_sizes; (void)n_in; (void)out_size; (void)ws_size;
  const float* x1 = (const float*)d_in[0];
  const float* x2 = (const float*)d_in[1];
  const float* Wq = (const float*)d_in[2];
  const float* bq = (const float*)d_in[3];
  const float* Wk = (const float*)d_in[4];
  const float* bk = (const float*)d_in[5];
  const float* Wv = (const float*)d_in[6];
  const float* bv = (const float*)d_in[7];
  const float* Wo = (const float*)d_in[8];
  const float* bo = (const float*)d_in[9];
  float* out = (float*)d_out;

  char* ws = (char*)d_ws;
  u16* x1b = (u16*)(ws);                       // 8 MB
  u16* x2b = (u16*)(ws + (8u  << 20));         // 8 MB
  u16* Wqb = (u16*)(ws + (16u << 20));         // 2 MB
  u16* Wkb = (u16*)(ws + (18u << 20));
  u16* Wvb = (u16*)(ws + (20u << 20));
  u16* Wob = (u16*)(ws + (22u << 20));
  u16* qb  = (u16*)(ws + (24u << 20));         // 8 MB
  u16* kb  = (u16*)(ws + (32u << 20));
  u16* vb  = (u16*)(ws + (40u << 20));
  u16* ob  = (u16*)(ws + (48u << 20));         // total 56 MB

  cast_all<<<dim3(512, 6), 256, 0, stream>>>(x1, x1b, x2, x2b, Wq, Wqb,
                                             Wk, Wkb, Wv, Wvb, Wo, Wob);

  const int Mrows = BB_ * NN_;  // 4096
  // Fused Q/K/V projections: one launch, grid.z selects the matmul.
  dim3 gqkv(Mrows / BM, DIM_ / BN, 3);  // (32, 8, 3) = 768 blocks
  gemm_qkv<<<gqkv, 512, 0, stream>>>(x1b, x2b, Wqb, bq, qb, Wkb, bk, kb, Wvb, bv, vb);

  dim3 ga(NN_ / QB, NHEADS_, BB_);  // (16, 16, 2)
  attn_fwd<<<ga, 512, 0, stream>>>(qb, kb, vb, ob);

  dim3 gg(Mrows / BM, DIM_ / BN);  // (32, 8)
  gemm_o<<<gg, 512, 0, stream>>>(ob, Wob, bo, out);
}

// Round 10
// 117.181 us; speedup vs baseline: 1.0690x; 1.0690x over previous
//
#include <hip/hip_runtime.h>
#include <stdint.h>

typedef unsigned short u16;
typedef __attribute__((ext_vector_type(4))) float f32x4;
typedef __attribute__((ext_vector_type(16))) float f32x16;
typedef __attribute__((ext_vector_type(8))) __bf16 bf16x8;
typedef __attribute__((ext_vector_type(8))) unsigned short u16x8;
typedef __attribute__((ext_vector_type(4))) unsigned short u16x4;

#define DIM_    1024
#define NHEADS_ 16
#define HD_     64
#define BB_     2
#define NN_     2048
#define MM_     2048

// 0.125 * log2(e): folded into Q projection so softmax runs in base-2.
#define QSCALE 0.180336884f

__device__ inline u16 f32_to_bf16u(float f) {
  union { float f; uint32_t u; } x; x.f = f;
  uint32_t r = x.u + 0x7FFFu + ((x.u >> 16) & 1u);
  return (u16)(r >> 16);
}

__device__ inline void gload_lds16(const u16* g, u16* l) {
  u16* gnc = const_cast<u16*>(g);
  __builtin_amdgcn_global_load_lds(
      (__attribute__((address_space(1))) void*)gnc,
      (__attribute__((address_space(3))) void*)l, 16, 0, 0);
}

__device__ inline uint32_t cvt_pk_bf16(float lo, float hi) {
  uint32_t r;
  asm("v_cvt_pk_bf16_f32 %0, %1, %2" : "=v"(r) : "v"(lo), "v"(hi));
  return r;
}
__device__ inline void permlane32_swap(uint32_t& a, uint32_t& b) {
  asm("v_permlane32_swap_b32 %0, %1" : "+v"(a), "+v"(b));
}

// ---------------- fused cast fp32 -> bf16 (all 6 tensors, one launch) ------
__global__ void cast_all(const float* s0, u16* d0, const float* s1, u16* d1,
                         const float* s2, u16* d2, const float* s3, u16* d3,
                         const float* s4, u16* d4, const float* s5, u16* d5) {
  const float* s; u16* d; int n4;
  switch (blockIdx.y) {
    case 0: s = s0; d = d0; n4 = (BB_ * NN_ * DIM_) / 4; break;
    case 1: s = s1; d = d1; n4 = (BB_ * MM_ * DIM_) / 4; break;
    case 2: s = s2; d = d2; n4 = (DIM_ * DIM_) / 4; break;
    case 3: s = s3; d = d3; n4 = (DIM_ * DIM_) / 4; break;
    case 4: s = s4; d = d4; n4 = (DIM_ * DIM_) / 4; break;
    default: s = s5; d = d5; n4 = (DIM_ * DIM_) / 4; break;
  }
  int stride = gridDim.x * blockDim.x;
  for (int i = blockIdx.x * blockDim.x + threadIdx.x; i < n4; i += stride) {
    float4 f = reinterpret_cast<const float4*>(s)[i];
    u16x4 u;
    u.x = f32_to_bf16u(f.x);
    u.y = f32_to_bf16u(f.y);
    u.z = f32_to_bf16u(f.z);
    u.w = f32_to_bf16u(f.w);
    reinterpret_cast<u16x4*>(d)[i] = u;
  }
}

// ---------------- GEMM core: C[M,N] = A * B^T + bias, 128x128 tile --------
#define BM 128
#define BN 128
#define BK 64

template <bool BF16OUT>
__device__ __forceinline__
void gemm_body(const u16* __restrict__ A, const u16* __restrict__ Bm,
               const float* __restrict__ bias, void* __restrict__ Cout,
               int M, int N, int K, float scale,
               u16* As /*2*BM*BK*/, u16* Bs /*2*BN*BK*/) {
  const int tid  = threadIdx.x;
  const int lane = tid & 63;
  const int wid  = tid >> 6;
  const int wr = wid >> 2, wc = wid & 3;          // 2 x 4 wave grid
  const int fr = lane & 15, fq = lane >> 4;
  const int bm = blockIdx.x, bn = blockIdx.y;
  const int lrow = lane >> 3;                     // 0..7
  const int scol = (((lane & 7) ^ lrow) * 8);     // pre-swizzled source col

  f32x4 acc[4][2];
  #pragma unroll
  for (int m = 0; m < 4; ++m)
    #pragma unroll
    for (int n = 0; n < 2; ++n)
      acc[m][n] = f32x4{0.f, 0.f, 0.f, 0.f};

  const int NT = K / BK;

  auto stage = [&](int buf, int t) {
    int k0 = t * BK;
    #pragma unroll
    for (int c = 0; c < 2; ++c) {
      int ch  = wid * 2 + c;           // 0..15
      int row = ch * 8 + lrow;         // 0..127
      gload_lds16(A  + (size_t)(bm * BM + row) * K + k0 + scol, &As[buf * BM * BK + ch * 512]);
      gload_lds16(Bm + (size_t)(bn * BN + row) * K + k0 + scol, &Bs[buf * BN * BK + ch * 512]);
    }
  };

  stage(0, 0);
  __syncthreads();
  int cur = 0;
  for (int t = 0; t < NT; ++t) {
    if (t + 1 < NT) stage(cur ^ 1, t + 1);
    #pragma unroll
    for (int ks = 0; ks < 2; ++ks) {
      bf16x8 af[4], bfr[2];
      #pragma unroll
      for (int m = 0; m < 4; ++m)
        af[m] = *reinterpret_cast<const bf16x8*>(
            &As[cur * BM * BK + (wr * 64 + m * 16 + fr) * BK + (((ks * 4 + fq) ^ (fr & 7)) * 8)]);
      #pragma unroll
      for (int n = 0; n < 2; ++n)
        bfr[n] = *reinterpret_cast<const bf16x8*>(
            &Bs[cur * BN * BK + (wc * 32 + n * 16 + fr) * BK + (((ks * 4 + fq) ^ (fr & 7)) * 8)]);
      __builtin_amdgcn_s_setprio(1);
      #pragma unroll
      for (int m = 0; m < 4; ++m)
        #pragma unroll
        for (int n = 0; n < 2; ++n)
          acc[m][n] = __builtin_amdgcn_mfma_f32_16x16x32_bf16(af[m], bfr[n], acc[m][n], 0, 0, 0);
      __builtin_amdgcn_s_setprio(0);
    }
    __syncthreads();
    cur ^= 1;
  }

  #pragma unroll
  for (int n = 0; n < 2; ++n) {
    int col = bn * BN + wc * 32 + n * 16 + fr;
    float bv = bias[col];
    #pragma unroll
    for (int m = 0; m < 4; ++m) {
      #pragma unroll
      for (int i = 0; i < 4; ++i) {
        int row = bm * BM + wr * 64 + m * 16 + fq * 4 + i;
        float v = (acc[m][n][i] + bv) * scale;
        if (BF16OUT)
          ((u16*)Cout)[(size_t)row * N + col] = f32_to_bf16u(v);
        else
          ((float*)Cout)[(size_t)row * N + col] = v;
      }
    }
  }
}

// Fused Q/K/V projection: grid.z selects {x1*Wq^T+bq, x2*Wk^T+bk, x2*Wv^T+bv}.
__global__ __launch_bounds__(512)
void gemm_qkv(const u16* __restrict__ x1b, const u16* __restrict__ x2b,
              const u16* __restrict__ Wqb, const float* __restrict__ bq, u16* qb,
              const u16* __restrict__ Wkb, const float* __restrict__ bk, u16* kb,
              const u16* __restrict__ Wvb, const float* __restrict__ bv, u16* vb) {
  __shared__ __align__(16) u16 As[2 * BM * BK];
  __shared__ __align__(16) u16 Bs[2 * BN * BK];
  const u16* A; const u16* W; const float* bias; u16* C; float scale;
  switch (blockIdx.z) {
    case 0:  A = x1b; W = Wqb; bias = bq; C = qb; scale = QSCALE; break;
    case 1:  A = x2b; W = Wkb; bias = bk; C = kb; scale = 1.0f;   break;
    default: A = x2b; W = Wvb; bias = bv; C = vb; scale = 1.0f;   break;
  }
  gemm_body<true>(A, W, bias, C, BB_ * NN_, DIM_, DIM_, scale, As, Bs);
}

// O projection (fp32 out).
__global__ __launch_bounds__(512)
void gemm_o(const u16* __restrict__ A, const u16* __restrict__ W,
            const float* __restrict__ bias, float* __restrict__ C) {
  __shared__ __align__(16) u16 As[2 * BM * BK];
  __shared__ __align__(16) u16 Bs[2 * BN * BK];
  gemm_body<false>(A, W, bias, C, BB_ * NN_, DIM_, DIM_, 1.0f, As, Bs);
}

// ---------------- flash attention, 32x32 MFMA ----------------
// 512 blocks (XCD-swizzled), 512 threads = 8 waves = 4 q-groups x 2 kv-halves.
// Swapped QK^T (mfma_32x32x16(K,Q) -> S^T[kv][q] in regs); P in-register via
// cvt_pk+permlane32_swap; no-max base-2 softmax; l via ones-A MFMA.
// 3-buffer LDS ring (48 KB -> 3 blocks/CU), prefetch depth 2, 1 barrier/tile.
// Epilogue: padded transpose with BARRIER-SEPARATED phases (R9 bug: Of
// overlays Od, and different wq groups' regions interleave -> must fence
// between the Od reads and the Of writes).
#define QB 128
#define KVB 64

__global__ __launch_bounds__(512)
void attn_fwd(const u16* __restrict__ qg, const u16* __restrict__ kg,
              const u16* __restrict__ vg, u16* __restrict__ og) {
  __shared__ __align__(16) u16 KVs[6 * KVB * HD_];   // 3 K bufs + 3 VT bufs = 48 KB
  const int tid = threadIdx.x, lane = tid & 63, wid = tid >> 6;
  const int hi = lane >> 5;          // half-wave index
  const int l31 = lane & 31;
  const int wq = wid >> 1, wk = wid & 1;

  // XCD-aware swizzle (bijective: 512 = 8 xcd * 16 r * 4 gg)
  int lin = blockIdx.x + gridDim.x * (blockIdx.y + gridDim.y * blockIdx.z);
  int xcd = lin & 7, slot = lin >> 3;
  int r = slot & 15, gg2 = slot >> 4;
  int g = xcd + 8 * gg2;             // bh group 0..31
  int h = g & 15, b = g >> 4;

  const size_t base_q  = (size_t)b * NN_ * DIM_ + (size_t)h * HD_;
  const size_t base_kv = (size_t)b * MM_ * DIM_ + (size_t)h * HD_;
  const int lrow = lane >> 3;
  const int scol = (((lane & 7) ^ lrow) * 8);   // pre-swizzled K source col

  // Q fragments, B-layout [16 d][32 q]: lane holds Q[q=l31][step*16+hi*8+j]
  bf16x8 qf[4];
  const int qrow = r * QB + wq * 32 + l31;
  #pragma unroll
  for (int step = 0; step < 4; ++step)
    qf[step] = *reinterpret_cast<const bf16x8*>(
        qg + base_q + (size_t)qrow * DIM_ + step * 16 + hi * 8);

  // all-ones A fragment (layout-independent) for the l row-sum MFMA
  bf16x8 onesf;
  #pragma unroll
  for (int j = 0; j < 8; ++j) onesf[j] = (__bf16)1.0f;

  f32x16 oacc[2];
  #pragma unroll
  for (int dgrp = 0; dgrp < 2; ++dgrp)
    #pragma unroll
    for (int rg = 0; rg < 16; ++rg) oacc[dgrp][rg] = 0.f;
  f32x16 lacc;
  #pragma unroll
  for (int rg = 0; rg < 16; ++rg) lacc[rg] = 0.f;

  const int NT = MM_ / KVB;

  auto stageK = [&](int buf, int t) {
    int kv0 = t * KVB;
    int row = wid * 8 + lrow;   // 0..63
    gload_lds16(kg + base_kv + (size_t)(kv0 + row) * DIM_ + scol,
                &KVs[buf * 4096 + wid * 512]);
  };
  auto loadV = [&](int t, u16x8& vpre) {
    int kv0 = t * KVB;
    vpre = *reinterpret_cast<const u16x8*>(vg + base_kv + (size_t)(kv0 + lane) * DIM_ + wid * 8);
  };
  auto writeVT = [&](int buf, const u16x8& vpre) {
    #pragma unroll
    for (int j = 0; j < 8; ++j)
      KVs[(3 + buf) * 4096 + (wid * 8 + j) * KVB + (((lane >> 3) ^ j) * 8) + (lane & 7)] = vpre[j];
  };

  union PB { uint32_t w[4]; bf16x8 v; };

  auto compute = [&](int buf) {
    const u16* Kb = &KVs[buf * 4096];
    const u16* Vb = &KVs[(3 + buf) * 4096];
    // ---- QK^T swapped (32x32x16): S^T[kv=wk half][q] ----
    f32x16 s;
    #pragma unroll
    for (int rg = 0; rg < 16; ++rg) s[rg] = 0.f;
    __builtin_amdgcn_s_setprio(1);
    #pragma unroll
    for (int step = 0; step < 4; ++step) {
      bf16x8 kf = *reinterpret_cast<const bf16x8*>(
          (const char*)Kb + (wk * 32 + l31) * 128 + (((step * 2 + hi) ^ (lane & 7)) * 16));
      s = __builtin_amdgcn_mfma_f32_32x32x16_bf16(kf, qf[step], s, 0, 0, 0);
    }
    __builtin_amdgcn_s_setprio(0);

    // ---- no-max softmax: p = exp2(s) ----
    float p[16];
    #pragma unroll
    for (int rg = 0; rg < 16; ++rg) p[rg] = __builtin_amdgcn_exp2f(s[rg]);

    // ---- pack P^T into PV B-frags in-register (cvt_pk + permlane32_swap) --
    PB pb[2];
    #pragma unroll
    for (int u = 0; u < 2; ++u) {
      uint32_t x0 = cvt_pk_bf16(p[u * 8 + 0], p[u * 8 + 1]);
      uint32_t y0 = cvt_pk_bf16(p[u * 8 + 4], p[u * 8 + 5]);
      permlane32_swap(x0, y0);
      uint32_t x1 = cvt_pk_bf16(p[u * 8 + 2], p[u * 8 + 3]);
      uint32_t y1 = cvt_pk_bf16(p[u * 8 + 6], p[u * 8 + 7]);
      permlane32_swap(x1, y1);
      pb[u].w[0] = x0; pb[u].w[1] = x1; pb[u].w[2] = y0; pb[u].w[3] = y1;
    }

    // ---- PV (32x32x16): O^T[d][q] += V^T[d][kv] P^T[kv][q]; l = 1^T P ----
    __builtin_amdgcn_s_setprio(1);
    #pragma unroll
    for (int u = 0; u < 2; ++u)
      lacc = __builtin_amdgcn_mfma_f32_32x32x16_bf16(onesf, pb[u].v, lacc, 0, 0, 0);
    #pragma unroll
    for (int dgrp = 0; dgrp < 2; ++dgrp)
      #pragma unroll
      for (int u = 0; u < 2; ++u) {
        bf16x8 vf = *reinterpret_cast<const bf16x8*>(
            (const char*)Vb + (dgrp * 32 + l31) * 128 +
            (((wk * 4 + u * 2 + hi) ^ (lane & 7)) * 16));
        oacc[dgrp] = __builtin_amdgcn_mfma_f32_32x32x16_bf16(vf, pb[u].v, oacc[dgrp], 0, 0, 0);
      }
    __builtin_amdgcn_s_setprio(0);
  };

  // prologue: stage tiles 0,1 into bufs 0,1
  {
    u16x8 v0, v1;
    loadV(0, v0);
    loadV(1, v1);
    stageK(0, 0);
    stageK(1, 1);
    writeVT(0, v0);
    writeVT(1, v1);
    __syncthreads();
  }

  // main loop: 3-buffer ring, prefetch t+2 while computing t, 1 barrier/tile.
  int cur = 0, stg = 2;
  for (int t = 0; t < NT; ++t) {
    u16x8 vpre;
    bool pre = (t + 2 < NT);
    if (pre) {
      loadV(t + 2, vpre);
      stageK(stg, t + 2);
    }
    compute(cur);
    if (pre) writeVT(stg, vpre);
    __syncthreads();
    cur = (cur == 2) ? 0 : cur + 1;
    stg = (stg == 2) ? 0 : stg + 1;
  }

  // ---- epilogue: cross-wk O/l reduction, padded transpose, 3 fenced phases --
  float* Od = (float*)&KVs[0];             // [128][65] f32 = 33280 B
  float* Ls = (float*)&KVs[0] + 128 * 65;  // [128] f32 (disjoint from Od & Of)
  u16*  Of  = (u16*)&KVs[0];               // [128][68] u16 overlay of Od region

  // phase 1: wk==1 publishes its partial O and l
  if (wk == 1) {
    #pragma unroll
    for (int dgrp = 0; dgrp < 2; ++dgrp)
      #pragma unroll
      for (int rg = 0; rg < 16; ++rg) {
        int d = dgrp * 32 + (rg & 3) + 8 * (rg >> 2) + 4 * hi;
        Od[(wq * 32 + l31) * 65 + d] = oacc[dgrp][rg];
      }
    if (hi == 0) Ls[wq * 32 + l31] = lacc[0];
  }
  __syncthreads();
  // phase 2: wk==0 reduces into registers and scales (reads only)
  if (wk == 0) {
    float inv = 1.f / (lacc[0] + Ls[wq * 32 + l31]);
    #pragma unroll
    for (int dgrp = 0; dgrp < 2; ++dgrp)
      #pragma unroll
      for (int rg = 0; rg < 16; ++rg) {
        int d = dgrp * 32 + (rg & 3) + 8 * (rg >> 2) + 4 * hi;
        oacc[dgrp][rg] = (oacc[dgrp][rg] + Od[(wq * 32 + l31) * 65 + d]) * inv;
      }
  }
  __syncthreads();  // ALL Od reads complete before Of overwrites the region
  // phase 3: wk==0 writes the bf16 transpose buffer
  if (wk == 0) {
    #pragma unroll
    for (int dgrp = 0; dgrp < 2; ++dgrp)
      #pragma unroll
      for (int rg = 0; rg < 16; ++rg) {
        int d = dgrp * 32 + (rg & 3) + 8 * (rg >> 2) + 4 * hi;
        Of[(wq * 32 + l31) * 68 + d] = f32_to_bf16u(oacc[dgrp][rg]);
      }
  }
  __syncthreads();
  // cooperative coalesced store: 128 q-rows x 128 B
  #pragma unroll
  for (int itr = 0; itr < 2; ++itr) {
    int idx = itr * 512 + tid;   // 0..1023
    int qq = idx >> 3;           // 0..127
    int ck = idx & 7;            // 16B chunk
    u16x8 v = *reinterpret_cast<const u16x8*>(&Of[qq * 68 + ck * 8]);
    *reinterpret_cast<u16x8*>(og + base_q + (size_t)(r * QB + qq) * DIM_ + ck * 8) = v;
  }
}

// ---------------- launch ----------------
extern "C" void kernel_launch(void* const* d_in, const int* in_sizes, int n_in,
                              void* d_out, int out_size, void* d_ws, size_t ws_size,
                              hipStream_t stream) {
  (void)in_sizes; (void)n_in; (void)out_size; (void)ws_size;
  const float* x1 = (const float*)d_in[0];
  const float* x2 = (const float*)d_in[1];
  const float* Wq = (const float*)d_in[2];
  const float* bq = (const float*)d_in[3];
  const float* Wk = (const float*)d_in[4];
  const float* bk = (const float*)d_in[5];
  const float* Wv = (const float*)d_in[6];
  const float* bv = (const float*)d_in[7];
  const float* Wo = (const float*)d_in[8];
  const float* bo = (const float*)d_in[9];
  float* out = (float*)d_out;

  char* ws = (char*)d_ws;
  u16* x1b = (u16*)(ws);                       // 8 MB
  u16* x2b = (u16*)(ws + (8u  << 20));         // 8 MB
  u16* Wqb = (u16*)(ws + (16u << 20));         // 2 MB
  u16* Wkb = (u16*)(ws + (18u << 20));
  u16* Wvb = (u16*)(ws + (20u << 20));
  u16* Wob = (u16*)(ws + (22u << 20));
  u16* qb  = (u16*)(ws + (24u << 20));         // 8 MB
  u16* kb  = (u16*)(ws + (32u << 20));
  u16* vb  = (u16*)(ws + (40u << 20));
  u16* ob  = (u16*)(ws + (48u << 20));         // total 56 MB

  cast_all<<<dim3(512, 6), 256, 0, stream>>>(x1, x1b, x2, x2b, Wq, Wqb,
                                             Wk, Wkb, Wv, Wvb, Wo, Wob);

  const int Mrows = BB_ * NN_;  // 4096
  // Fused Q/K/V projections: one launch, grid.z selects the matmul.
  dim3 gqkv(Mrows / BM, DIM_ / BN, 3);  // (32, 8, 3) = 768 blocks
  gemm_qkv<<<gqkv, 512, 0, stream>>>(x1b, x2b, Wqb, bq, qb, Wkb, bk, kb, Wvb, bv, vb);

  dim3 ga(NN_ / QB, NHEADS_, BB_);  // (16, 16, 2)
  attn_fwd<<<ga, 512, 0, stream>>>(qb, kb, vb, ob);

  dim3 gg(Mrows / BM, DIM_ / BN);  // (32, 8)
  gemm_o<<<gg, 512, 0, stream>>>(ob, Wob, bo, out);
}